// Round 1
// 203.153 us; speedup vs baseline: 1.0051x; 1.0051x over previous
//
#include <hip/hip_runtime.h>
#include <hip/hip_bf16.h>
#include <stdint.h>

typedef unsigned short ushort_t;
using short8   = __attribute__((ext_vector_type(8))) short;
using float4v  = __attribute__((ext_vector_type(4))) float;
using uint4v   = __attribute__((ext_vector_type(4))) unsigned;

#define BSH    6          // bucket = 64 consecutive dst nodes
#define BUCKW  64
#define CAP    1536       // per-bucket capacity (avg 1024, +16 sigma)
#define NBMAX  2048
#define BINB   256        // binning blocks

__device__ __forceinline__ float bf2f(ushort_t u) {
    union { unsigned int i; float f; } v;
    v.i = ((unsigned int)u) << 16;
    return v.f;
}
__device__ __forceinline__ ushort_t f2b(float f) {
    union { float f; unsigned int i; } v;
    v.f = f;
    unsigned int u = v.i;
    unsigned int r = (u + 0x7fffu + ((u >> 16) & 1u)) >> 16;   // RNE
    return (ushort_t)r;
}
__device__ __forceinline__ float blo2f(unsigned v) {   // low bf16 of dword
    union { unsigned i; float f; } u; u.i = v << 16; return u.f;
}
__device__ __forceinline__ float bhi2f(unsigned v) {   // high bf16 of dword
    union { unsigned i; float f; } u; u.i = v & 0xFFFF0000u; return u.f;
}

// ---------------------------------------------------------------------------
// prep_k: heterogeneous roles, 512 threads.
//  blocks [0, TB):   register-direct transpose, 128 nodes each:
//                    thread = (node, 16-dim block). 16 independent stride-N
//                    loads batched in regs (full MLP), pack bf16 pairs,
//                    2x16B direct global stores (no LDS, no barrier).
//                    Sibling dim-blocks fill lines -> L2 merges partials.
//                    (block 0 also converts weights to bf16)
//  blocks [TB, +BINB): two-sweep binning, 8-wide edge batching per thread so
//                    each wave keeps ~8 loads in flight (was 1 -> latency
//                    chain). Block-private spans => coalesced write-back.
//                    gcur pre-zeroed by hipMemsetAsync; bases bucket-relative.
// ---------------------------------------------------------------------------
__global__ __launch_bounds__(512) void prep_k(
        const float* __restrict__ inp, ushort_t* __restrict__ X, int N,
        const float* __restrict__ W1, const float* __restrict__ W2,
        ushort_t* __restrict__ w1b, ushort_t* __restrict__ w2b,
        const int* __restrict__ src, const int* __restrict__ dst,
        int* __restrict__ gcur, unsigned* __restrict__ bin, int E,
        int NB, int TB) {
    __shared__ int lcnt[NBMAX];
    __shared__ int gbase[NBMAX];
    __shared__ int lcur[NBMAX];
    int tid = threadIdx.x;

    if ((int)blockIdx.x < TB) {
        // ---------------- transpose role (register-direct) ----------------
        if (blockIdx.x == 0) {
            for (int i = tid; i < 8192; i += 512) {
                w1b[i] = f2b(W1[i]);
                w2b[i] = f2b(W2[i]);
            }
        }
        int db = tid >> 7;                  // 0..3: 16-dim block
        int nl = tid & 127;                 // node within block tile
        int nc = blockIdx.x * 128 + nl;
        if (nc < N) {
            const float* ip = inp + (size_t)(db * 16) * N + nc;
            float v[16];
#pragma unroll
            for (int r = 0; r < 16; ++r)    // 16 independent loads -> all in flight
                v[r] = ip[(size_t)r * N];
            unsigned dw[8];
#pragma unroll
            for (int j = 0; j < 8; ++j)
                dw[j] = (unsigned)f2b(v[2 * j]) | ((unsigned)f2b(v[2 * j + 1]) << 16);
            unsigned* xp = (unsigned*)X + (size_t)nc * 32 + db * 8;
            uint4v a = {dw[0], dw[1], dw[2], dw[3]};
            uint4v b = {dw[4], dw[5], dw[6], dw[7]};
            *(uint4v*)(xp)     = a;
            *(uint4v*)(xp + 4) = b;
        }
    } else {
        // ---------------- binning role ----------------
        int bid   = blockIdx.x - TB;
        int chunk = (E + BINB - 1) / BINB;
        int s0 = bid * chunk;
        int s1 = s0 + chunk;
        if (s1 > E) s1 = E;

        for (int b = tid; b < NB; b += 512) lcnt[b] = 0;
        __syncthreads();

        // sweep 1: histogram, 8-wide batched loads
        int e = s0 + tid;
        for (; e + 512 * 7 < s1; e += 512 * 8) {
            int d[8];
#pragma unroll
            for (int k = 0; k < 8; ++k) d[k] = dst[e + 512 * k];
#pragma unroll
            for (int k = 0; k < 8; ++k) atomicAdd(&lcnt[d[k] >> BSH], 1);
        }
        for (; e < s1; e += 512)
            atomicAdd(&lcnt[dst[e] >> BSH], 1);
        __syncthreads();

        for (int b = tid; b < NB; b += 512) {
            int c = lcnt[b];
            gbase[b] = c ? atomicAdd(&gcur[b], c) : 0;   // relative base
            lcur[b]  = 0;
        }
        __syncthreads();

        // sweep 2: placement, 8-wide batched loads
        e = s0 + tid;
        for (; e + 512 * 7 < s1; e += 512 * 8) {
            int d[8], s[8];
#pragma unroll
            for (int k = 0; k < 8; ++k) {
                d[k] = dst[e + 512 * k];
                s[k] = src[e + 512 * k];
            }
#pragma unroll
            for (int k = 0; k < 8; ++k) {
                int b   = d[k] >> BSH;
                int pos = gbase[b] + atomicAdd(&lcur[b], 1);
                if (pos < CAP)   // overflow guard (statistically unreachable)
                    bin[(size_t)b * CAP + pos] =
                        ((unsigned)(d[k] & (BUCKW - 1)) << 24) | (unsigned)s[k];
            }
        }
        for (; e < s1; e += 512) {
            int dv = dst[e];
            int b  = dv >> BSH;
            int pos = gbase[b] + atomicAdd(&lcur[b], 1);
            if (pos < CAP)
                bin[(size_t)b * CAP + pos] =
                    ((unsigned)(dv & (BUCKW - 1)) << 24) | (unsigned)src[e];
        }
    }
}

// ---------------------------------------------------------------------------
// Per-bucket aggregation: counting-sort bucket edges by local node in LDS,
// then one wave per node. Gather uses DWORD-PAIR mapping: lanes 0-31 read
// row of edge e (32x4B), lanes 32-63 row of edge e+1 => 2 edges per load
// instr, 16 edges in flight at unroll 8 (2x R9 concurrency). Cross-half
// combine via shfl(+32); agg stored bf16 (halves write traffic).
// ---------------------------------------------------------------------------
__global__ __launch_bounds__(256) void bagg_k(
        const unsigned* __restrict__ Xu, const unsigned* __restrict__ bin,
        const int* __restrict__ gcur, unsigned* __restrict__ aggu, int N) {
    __shared__ unsigned sl[CAP];      // 6 KB
    __shared__ int ecnt[BUCKW];
    __shared__ int sc[BUCKW];
    __shared__ int ecur[BUCKW];
    int tid = threadIdx.x;
    int b   = blockIdx.x;
    int lo  = b << BSH;

    int cnt = gcur[b];
    if (cnt > CAP) cnt = CAP;
    const unsigned* bb = bin + (size_t)b * CAP;

    if (tid < BUCKW) ecnt[tid] = 0;
    __syncthreads();

    for (int i = tid; i < cnt; i += 256)
        atomicAdd(&ecnt[bb[i] >> 24], 1);
    __syncthreads();

    if (tid < BUCKW) sc[tid] = ecnt[tid];
    __syncthreads();
#pragma unroll
    for (int off = 1; off < BUCKW; off <<= 1) {
        int v = 0;
        if (tid < BUCKW && tid >= off) v = sc[tid - off];
        __syncthreads();
        if (tid < BUCKW) sc[tid] += v;
        __syncthreads();
    }
    if (tid < BUCKW) { sc[tid] -= ecnt[tid]; ecur[tid] = 0; }   // exclusive
    __syncthreads();

    for (int i = tid; i < cnt; i += 256) {
        unsigned p = bb[i];
        int nl  = (int)(p >> 24);
        int pos = sc[nl] + atomicAdd(&ecur[nl], 1);
        sl[pos] = p;
    }
    __syncthreads();

    int wave = tid >> 6;               // 0..3
    int lane = tid & 63;
    int half = lane >> 5;              // 0: even edges, 1: odd edges
    int c2   = lane & 31;              // dword index within row (2 dims)

    for (int n = wave; n < BUCKW; n += 4) {
        int node = lo + n;
        if (node >= N) break;
        int s0 = sc[n];
        int c  = ecnt[n];
        float alo0 = 0.f, ahi0 = 0.f, alo1 = 0.f, ahi1 = 0.f;
        int i = 0;
        for (; i + 16 <= c; i += 16) {
            unsigned p0 = sl[s0 + i +  0 + half], p1 = sl[s0 + i +  2 + half];
            unsigned p2 = sl[s0 + i +  4 + half], p3 = sl[s0 + i +  6 + half];
            unsigned p4 = sl[s0 + i +  8 + half], p5 = sl[s0 + i + 10 + half];
            unsigned p6 = sl[s0 + i + 12 + half], p7 = sl[s0 + i + 14 + half];
            unsigned v0 = Xu[(size_t)(p0 & 0xFFFFFFu) * 32 + c2];
            unsigned v1 = Xu[(size_t)(p1 & 0xFFFFFFu) * 32 + c2];
            unsigned v2 = Xu[(size_t)(p2 & 0xFFFFFFu) * 32 + c2];
            unsigned v3 = Xu[(size_t)(p3 & 0xFFFFFFu) * 32 + c2];
            unsigned v4 = Xu[(size_t)(p4 & 0xFFFFFFu) * 32 + c2];
            unsigned v5 = Xu[(size_t)(p5 & 0xFFFFFFu) * 32 + c2];
            unsigned v6 = Xu[(size_t)(p6 & 0xFFFFFFu) * 32 + c2];
            unsigned v7 = Xu[(size_t)(p7 & 0xFFFFFFu) * 32 + c2];
            alo0 += blo2f(v0); ahi0 += bhi2f(v0);
            alo1 += blo2f(v1); ahi1 += bhi2f(v1);
            alo0 += blo2f(v2); ahi0 += bhi2f(v2);
            alo1 += blo2f(v3); ahi1 += bhi2f(v3);
            alo0 += blo2f(v4); ahi0 += bhi2f(v4);
            alo1 += blo2f(v5); ahi1 += bhi2f(v5);
            alo0 += blo2f(v6); ahi0 += bhi2f(v6);
            alo1 += blo2f(v7); ahi1 += bhi2f(v7);
        }
        for (; i + 2 <= c; i += 2) {
            unsigned p = sl[s0 + i + half];
            unsigned v = Xu[(size_t)(p & 0xFFFFFFu) * 32 + c2];
            alo0 += blo2f(v); ahi0 += bhi2f(v);
        }
        if (i + half < c) {            // odd tail: half 0 only
            unsigned p = sl[s0 + i + half];
            unsigned v = Xu[(size_t)(p & 0xFFFFFFu) * 32 + c2];
            alo1 += blo2f(v); ahi1 += bhi2f(v);
        }
        float alo = alo0 + alo1;
        float ahi = ahi0 + ahi1;
        float blo = __shfl(alo, lane + 32);
        float bhi = __shfl(ahi, lane + 32);
        if (half == 0) {
            alo += blo; ahi += bhi;
            aggu[(size_t)node * 32 + c2] =
                (unsigned)f2b(alo) | ((unsigned)f2b(ahi) << 16);
        }
    }
}

// ---------------------------------------------------------------------------
// Fused 2-layer MLP via bf16 MFMA 16x16x32 (fp32 acc). agg is bf16 [N][64]
// => A-fragments load directly as short8 (no cvt, half the fetch).
// Frag maps (verified, guide §3):
//   A[m=lane&15][k=(lane>>4)*8+j], B[k=(lane>>4)*8+j][n=lane&15],
//   D[m=(lane>>4)*4+r][n=lane&15]
// ---------------------------------------------------------------------------
#define HPITCH 136

__global__ __launch_bounds__(256) void mlp_k(
        const ushort_t* __restrict__ aggb,
        const ushort_t* __restrict__ W1, const float* __restrict__ b1,
        const ushort_t* __restrict__ W2, const float* __restrict__ b2,
        float* __restrict__ out, int N) {
    __shared__ ushort_t h_s[4][16 * HPITCH];

    int wave = threadIdx.x >> 6;
    int lane = threadIdx.x & 63;
    int row  = lane & 15;
    int quad = lane >> 4;
    int n0   = blockIdx.x * 64 + wave * 16;

    int anode = n0 + row;
    if (anode > N - 1) anode = N - 1;
    const ushort_t* ap = aggb + (size_t)anode * 64;
    short8 a0 = *(const short8*)(ap + quad * 8);
    short8 a1 = *(const short8*)(ap + 32 + quad * 8);

    float4v zero = {0.f, 0.f, 0.f, 0.f};
    float4v acc[8];
#pragma unroll
    for (int nt = 0; nt < 8; ++nt) acc[nt] = zero;

#pragma unroll
    for (int nt = 0; nt < 8; ++nt) {
        const ushort_t* wp = W1 + (size_t)(nt * 16 + row) * 64 + quad * 8;
        short8 bf0 = *(const short8*)(wp);
        short8 bf1 = *(const short8*)(wp + 32);
        acc[nt] = __builtin_amdgcn_mfma_f32_16x16x32_bf16(a0, bf0, acc[nt], 0, 0, 0);
        acc[nt] = __builtin_amdgcn_mfma_f32_16x16x32_bf16(a1, bf1, acc[nt], 0, 0, 0);
    }

    ushort_t* hw = h_s[wave];
#pragma unroll
    for (int nt = 0; nt < 8; ++nt) {
        float bias = b1[nt * 16 + row];
#pragma unroll
        for (int r = 0; r < 4; ++r) {
            float v = acc[nt][r] + bias;
            v = v > 0.f ? v : 0.f;
            hw[(quad * 4 + r) * HPITCH + nt * 16 + row] = f2b(v);
        }
    }
    __syncthreads();

    short8 a2[4];
#pragma unroll
    for (int kt = 0; kt < 4; ++kt)
        a2[kt] = *(const short8*)(hw + row * HPITCH + kt * 32 + quad * 8);

    float4v acc2[4];
#pragma unroll
    for (int nt = 0; nt < 4; ++nt) acc2[nt] = zero;

#pragma unroll
    for (int nt = 0; nt < 4; ++nt) {
#pragma unroll
        for (int kt = 0; kt < 4; ++kt) {
            short8 bfr = *(const short8*)(W2 + (size_t)(nt * 16 + row) * 128 +
                                          kt * 32 + quad * 8);
            acc2[nt] = __builtin_amdgcn_mfma_f32_16x16x32_bf16(a2[kt], bfr, acc2[nt], 0, 0, 0);
        }
    }

    int node = n0 + quad * 4;
    if (node < N) {
#pragma unroll
        for (int nt = 0; nt < 4; ++nt) {
            int ko = nt * 16 + row;
            float bias = b2[ko];
            float4v pk;
#pragma unroll
            for (int r = 0; r < 4; ++r) pk[r] = acc2[nt][r] + bias;
            *(float4v*)(out + (size_t)ko * N + node) = pk;
        }
    }
}

// ---------------------------------------------------------------------------
extern "C" void kernel_launch(void* const* d_in, const int* in_sizes, int n_in,
                              void* d_out, int out_size, void* d_ws, size_t ws_size,
                              hipStream_t stream) {
    const float* inp = (const float*)d_in[0];   // [64][N] fp32
    const int*   src = (const int*)d_in[1];
    const int*   dst = (const int*)d_in[2];
    const float* W1  = (const float*)d_in[3];   // [128][64] fp32
    const float* b1  = (const float*)d_in[4];   // [128] fp32
    const float* W2  = (const float*)d_in[5];   // [64][128] fp32
    const float* b2  = (const float*)d_in[6];   // [64] fp32
    float* out = (float*)d_out;                 // [64][N] fp32

    int N  = in_sizes[0] / 64;
    int E  = in_sizes[1];
    int NB = (N + BUCKW - 1) >> BSH;            // 1563 for N=100000 (<= NBMAX)

    // ws: aggb bf16[N*64] (12.8 MB) + w1b/w2b bf16 (32 KB) + gcur int[NBMAX]
    ushort_t* aggb = (ushort_t*)d_ws;
    ushort_t* w1b  = aggb + (size_t)N * 64;
    ushort_t* w2b  = w1b + 8192;
    int*      gcur = (int*)(w2b + 8192);

    // d_out staging (dead before mlp_k overwrites d_out):
    //   X bf16[N*64] (12.8 MB) | bin u32[NB*CAP] (9.6 MB)  — total 22.4 MB
    char*     ob  = (char*)d_out;
    ushort_t* X   = (ushort_t*)ob;
    unsigned* bin = (unsigned*)(ob + (size_t)N * 64 * 2);

    hipMemsetAsync(gcur, 0, NB * sizeof(int), stream);   // relative cursors

    int TB = (N + 127) / 128;
    prep_k<<<TB + BINB, 512, 0, stream>>>(inp, X, N, W1, W2, w1b, w2b,
                                          src, dst, gcur, bin, E, NB, TB);

    bagg_k<<<NB, 256, 0, stream>>>((const unsigned*)X, bin, gcur,
                                   (unsigned*)aggb, N);

    int tb = (N + 63) / 64;
    mlp_k<<<tb, 256, 0, stream>>>(aggb, w1b, b1, w2b, b2, out, N);
}